// Round 12
// baseline (198.143 us; speedup 1.0000x reference)
//
#include <hip/hip_runtime.h>
#include <hip/hip_bf16.h>
#include <hip/hip_fp16.h>

#define IN_DIM 4096
#define OUT_DIM 4096
#define HAD_SCALE_F 0.08838834764831845f   // 2^-3.5

typedef int   i32x4  __attribute__((ext_vector_type(4)));
typedef int   i32x16 __attribute__((ext_vector_type(16)));
typedef float f32x4  __attribute__((ext_vector_type(4)));

// ---------------------------------------------------------------------------
// Kernel A (round-12): FWHT with 16 elems/thread. 8 threads per 128-block:
// strides 1..8 in-register (4 stages, VALU), strides 16/32/64 via 3
// __shfl_xor masks x 16 elems = 48 shfl/thread (was 96 -> LDS-pipe bound).
// Element (t&7)*16+i of block t>>3 = global elem t*16+i -> coalesced 16B/thr.
// Quantization identical to round 8: s_a = rowmax/127, rowsum = s_a*sum(q).
// ---------------------------------------------------------------------------
__global__ __launch_bounds__(256)
void had_rows_q(const float* __restrict__ x, int* __restrict__ aq,
                float* __restrict__ rowsum, float* __restrict__ srow)
{
    __shared__ float wmx[4];
    __shared__ int   wqs[4];
    const int tid = threadIdx.x;
    const int wv  = tid >> 6;
    const size_t row = blockIdx.x;
    const float* xr = x + row * IN_DIM + tid * 16;

    float e[16];
    #pragma unroll
    for (int v = 0; v < 4; ++v) {
        const float4 f = ((const float4*)xr)[v];
        e[v*4+0] = f.x; e[v*4+1] = f.y; e[v*4+2] = f.z; e[v*4+3] = f.w;
    }

    // FWHT-16 in-register (strides 1,2,4,8)
    #pragma unroll
    for (int s = 1; s < 16; s <<= 1) {
        #pragma unroll
        for (int i = 0; i < 16; ++i) {
            if (!(i & s)) {
                const float u = e[i], w2 = e[i | s];
                e[i]     = u + w2;
                e[i | s] = u - w2;
            }
        }
    }
    // strides 16,32,64 -> lane-xor masks 1,2,4 (8 threads per block, same wave)
    #pragma unroll
    for (int m = 1; m <= 4; m <<= 1) {
        const float sgn = (tid & m) ? -1.0f : 1.0f;
        #pragma unroll
        for (int i = 0; i < 16; ++i) {
            const float p = __shfl_xor(e[i], m, 64);
            e[i] = fmaf(sgn, e[i], p);
        }
    }

    float smax = 0.f;
    #pragma unroll
    for (int i = 0; i < 16; ++i) {
        e[i] *= HAD_SCALE_F;
        smax = fmaxf(smax, fabsf(e[i]));
    }
    #pragma unroll
    for (int off = 32; off > 0; off >>= 1)
        smax = fmaxf(smax, __shfl_xor(smax, off, 64));
    if ((tid & 63) == 0) wmx[wv] = smax;
    __syncthreads();
    const float mx  = fmaxf(fmaxf(wmx[0], wmx[1]), fmaxf(wmx[2], wmx[3]));
    const float inv = (mx > 0.f) ? 127.0f / mx : 0.f;
    const float sa  = mx * (1.0f / 127.0f);

    int qsum = 0;
    int pk[4];
    #pragma unroll
    for (int g2 = 0; g2 < 4; ++g2) {
        const int q0 = (int)rintf(e[g2*4+0] * inv);
        const int q1 = (int)rintf(e[g2*4+1] * inv);
        const int q2 = (int)rintf(e[g2*4+2] * inv);
        const int q3 = (int)rintf(e[g2*4+3] * inv);
        qsum += (q0 + q1) + (q2 + q3);
        pk[g2] = (q0 & 0xFF) | ((q1 & 0xFF) << 8) | ((q2 & 0xFF) << 16) | (q3 << 24);
    }
    *(int4*)&aq[row * (IN_DIM / 4) + tid * 4] = make_int4(pk[0], pk[1], pk[2], pk[3]);

    #pragma unroll
    for (int off = 32; off > 0; off >>= 1) qsum += __shfl_xor(qsum, off, 64);
    if ((tid & 63) == 0) wqs[wv] = qsum;
    __syncthreads();
    if (tid == 0) {
        rowsum[row] = sa * (float)((wqs[0] + wqs[1]) + (wqs[2] + wqs[3]));
        srow[row]   = sa;
    }
}

// ---------------------------------------------------------------------------
// Kernel B: unpack int4 nibbles -> int8 weight matrix [OUT][IN] row-major.
// ---------------------------------------------------------------------------
__global__ __launch_bounds__(256)
void unpack_w8(const int* __restrict__ wp, signed char* __restrict__ wf8)
{
    const int gid = blockIdx.x * 256 + threadIdx.x;
    const int n   = gid >> 9;
    const int k0  = (gid & 511) * 8;
    const int4 p  = *(const int4*)(wp + (size_t)n * (IN_DIM / 2) + (k0 >> 1));
    const unsigned lo = (unsigned)(p.x & 15) | ((unsigned)((p.x >> 4) & 15) << 8)
                      | ((unsigned)(p.y & 15) << 16) | ((unsigned)((p.y >> 4) & 15) << 24);
    const unsigned hi = (unsigned)(p.z & 15) | ((unsigned)((p.z >> 4) & 15) << 8)
                      | ((unsigned)(p.w & 15) << 16) | ((unsigned)((p.w >> 4) & 15) << 24);
    *(uint2*)(wf8 + (size_t)n * IN_DIM + k0) = make_uint2(lo, hi);
}

// ---------------------------------------------------------------------------
// Kernel C: 256x256 int8 GEMM, R8 4-window schedule, mfma_i32_32x32x32_i8
// (round-12 change: 4404 vs 3944 TOPS -> MFMA/region 2612->2342 cyc; LDS
// traffic byte-identical). Wave tile 128x64 = 4 Mb x 2 Nb 32-blocks.
// A-frag: lane row = l&31, k = (l>>5)*16+e; B symmetric (col = l&31).
// C: col = lane&31, row = (reg&3) + 8*(reg>>2) + 4*(lane>>5).
// Same XOR swizzle (slot = chunk ^ (row&7); 8 consecutive lanes = 8 distinct
// slots -> 0 conflicts), same stage sets / vm counts / barriers as R8.
// ---------------------------------------------------------------------------
#define NT (IN_DIM / 128)   // 32 K-regions
#define NI (NT / 2)         // 16 iterations, 2 regions each

#define BAR()        asm volatile("s_barrier" ::: "memory")
#define WAIT_VM(N)   asm volatile("s_waitcnt vmcnt(" #N ")" ::: "memory")

// LDS: A0 @ 0, B0 @ 32768, A1 @ 65536, B1 @ 98304 (each 32 KiB = 256 rows x 128 B)
#define STAGE_A(p, R, kt) __builtin_amdgcn_global_load_lds( \
    (const __attribute__((address_space(1))) void*)(sA + (((size_t)(R)) << 18) + (((size_t)((kt) & 31)) << 7)), \
    (__attribute__((address_space(3))) void*)(smem + (p) * 65536 + (R) * 8192 + dstA), 16, 0, 0)
#define STAGE_B(p, R, kt) __builtin_amdgcn_global_load_lds( \
    (const __attribute__((address_space(1))) void*)(sB + (((size_t)(R)) << 18) + (((size_t)((kt) & 31)) << 7)), \
    (__attribute__((address_space(3))) void*)(smem + (p) * 65536 + (R) * 8192 + dstB), 16, 0, 0)

#define LDA(p, Mb, ks) (*(const i32x4*)(smem + (p)*65536 + (Mb)*4096 + (aBase ^ ((ks) << 5))))
#define LDB(p, Nb, ks) (*(const i32x4*)(smem + (p)*65536 + (Nb)*4096 + (bBase ^ ((ks) << 5))))

#define LOAD_A_TO(dst, p, mq) do { \
    _Pragma("unroll") for (int b = 0; b < 2; ++b) \
    _Pragma("unroll") for (int ks = 0; ks < 4; ++ks) \
        dst[b][ks] = LDA(p, (mq)*2 + b, ks); \
    } while (0)

#define LOAD_B(p, nq) do { \
    _Pragma("unroll") for (int ks = 0; ks < 4; ++ks) \
        bfr[nq][ks] = LDB(p, nq, ks); \
    } while (0)

#define MFMA_Q(abuf, mq, nq) do { \
    __builtin_amdgcn_s_setprio(1); \
    _Pragma("unroll") for (int b = 0; b < 2; ++b) \
    _Pragma("unroll") for (int ks = 0; ks < 4; ++ks) \
        acc[(mq)*2+b][nq] = __builtin_amdgcn_mfma_i32_32x32x32_i8( \
            abuf[b][ks], bfr[nq][ks], acc[(mq)*2+b][nq], 0, 0, 0); \
    __builtin_amdgcn_s_setprio(0); \
} while (0)

__global__ __launch_bounds__(512, 2)
void gemm_i8(const signed char* __restrict__ Aq, const signed char* __restrict__ Bw,
             const float* __restrict__ wscale, const float* __restrict__ wadd,
             const float* __restrict__ bias, const float* __restrict__ rowsum,
             const float* __restrict__ srow, float* __restrict__ out)
{
    __shared__ char smem[131072];

    const int tid  = threadIdx.x;
    const int lane = tid & 63;
    const int w    = tid >> 6;     // wave 0..7
    const int wm   = w >> 2;       // 0..1
    const int wn   = w & 3;        // 0..3

    // XCD-aware bijective swizzle: 512 wgs, 8 XCDs, 64 per XCD
    const int bid = blockIdx.x;
    const int wg  = (bid & 7) * 64 + (bid >> 3);
    const int m0  = (wg >> 4) * 256;   // M/256 = 32
    const int n0  = (wg & 15) * 256;   // N/256 = 16

    // ---- staging addresses (pre-swizzled source, linear LDS dest) ----
    const int rt = tid >> 3;
    const int ct = (tid & 7) ^ (rt & 7);
    const signed char* sA = Aq + (size_t)(m0 + rt) * IN_DIM + ct * 16;
    const signed char* sB = Bw + (size_t)(n0 + rt) * IN_DIM + ct * 16;
    const int dstA = w * 1024;
    const int dstB = 32768 + w * 1024;

    // ---- fragment read offsets (swizzled), 32x32 shape ----
    const int r32 = lane & 31, h = lane >> 5;
    const int sl  = (h ^ (r32 & 7)) << 4;
    const int aBase = (wm * 128 + r32) * 128 + sl;
    const int bBase = 32768 + (wn * 64 + r32) * 128 + sl;

    i32x4 afrA[2][4], afrB[2][4], bfr[2][4];
    i32x16 acc[4][2] = {};

    // ---- prologue: region0 -> buf0, region1 -> buf1 ----
    #pragma unroll
    for (int R = 0; R < 4; ++R) { STAGE_A(0, R, 0); STAGE_B(0, R, 0); }
    #pragma unroll
    for (int R = 0; R < 4; ++R) { STAGE_A(1, R, 1); STAGE_B(1, R, 1); }
    WAIT_VM(8);
    BAR();
    LOAD_B(0, 0);
    LOAD_A_TO(afrA, 0, 0);

    #pragma unroll 1
    for (int it = 0; it < NI; ++it) {
        const int kt1 = 2 * it + 1;
        const int kt2 = (2 * it + 2) & (NT - 1);
        const int kt3 = (2 * it + 3) & (NT - 1);

        // ---- W1: MFMA b0 m-half0 | read b0 nq1,h1 | stage b1 {Br2,r3, Ar1,r3}(kt1)
        LOAD_B(0, 1);
        if (it) { STAGE_B(1, 2, kt1); STAGE_B(1, 3, kt1);
                  STAGE_A(1, 1, kt1); STAGE_A(1, 3, kt1); }
        MFMA_Q(afrA, 0, 0);
        LOAD_A_TO(afrB, 0, 1);
        MFMA_Q(afrA, 0, 1);
        if (it) { WAIT_VM(2); } else { WAIT_VM(0); }
        BAR();

        // ---- W2: MFMA b0 m-half1 | read b1 nq0,h0 | stage b0 {Br0,r1, Ar0,r2}(kt2)
        STAGE_B(0, 0, kt2); STAGE_B(0, 1, kt2);
        MFMA_Q(afrB, 1, 0);
        LOAD_B(1, 0);
        LOAD_A_TO(afrA, 1, 0);
        STAGE_A(0, 0, kt2); STAGE_A(0, 2, kt2);
        MFMA_Q(afrB, 1, 1);
        WAIT_VM(4);
        BAR();

        // ---- W3: MFMA b1 m-half0 | read b1 nq1,h1 | stage b0 {Br2,r3, Ar1,r3}(kt2)
        STAGE_B(0, 2, kt2); STAGE_B(0, 3, kt2);
        MFMA_Q(afrA, 0, 0);
        LOAD_B(1, 1);
        LOAD_A_TO(afrB, 1, 1);
        STAGE_A(0, 1, kt2); STAGE_A(0, 3, kt2);
        MFMA_Q(afrA, 0, 1);
        WAIT_VM(2);
        BAR();

        // ---- W4: MFMA b1 m-half1 | read b0' nq0,h0 | stage b1 {Br0,r1, Ar0,r2}(kt3)
        STAGE_B(1, 0, kt3); STAGE_B(1, 1, kt3);
        MFMA_Q(afrB, 1, 0);
        LOAD_B(0, 0);
        LOAD_A_TO(afrA, 0, 0);
        STAGE_A(1, 0, kt3); STAGE_A(1, 2, kt3);
        MFMA_Q(afrB, 1, 1);
        WAIT_VM(4);
        BAR();
    }

    // ---- epilogue: y = srow[m]*wscale[n]*acc + wadd[n]*rowsum[m] + bias[n]
    // 32x32 C: col = lane&31, row = (reg&3) + 8*(reg>>2) + 4*(lane>>5)
    #pragma unroll
    for (int Nb = 0; Nb < 2; ++Nb) {
        const int col = n0 + wn * 64 + Nb * 32 + r32;
        const float sc = wscale[col];
        const float ad = wadd[col];
        const float bi = bias[col];
        #pragma unroll
        for (int Mb = 0; Mb < 4; ++Mb) {
            #pragma unroll
            for (int q = 0; q < 4; ++q) {
                const int rbase = m0 + wm * 128 + Mb * 32 + q * 8 + h * 4;
                const float4 rs4 = *(const float4*)&rowsum[rbase];
                const float4 sr4 = *(const float4*)&srow[rbase];
                #pragma unroll
                for (int j = 0; j < 4; ++j) {
                    const float rs = (j == 0) ? rs4.x : (j == 1) ? rs4.y : (j == 2) ? rs4.z : rs4.w;
                    const float sr = (j == 0) ? sr4.x : (j == 1) ? sr4.y : (j == 2) ? sr4.z : sr4.w;
                    out[(size_t)(rbase + j) * OUT_DIM + col] =
                        (float)acc[Mb][Nb][q * 4 + j] * (sc * sr) + ad * rs + bi;
                }
            }
        }
    }
}

// ---------------------------------------------------------------------------
extern "C" void kernel_launch(void* const* d_in, const int* in_sizes, int n_in,
                              void* d_out, int out_size, void* d_ws, size_t ws_size,
                              hipStream_t stream)
{
    const float* x      = (const float*)d_in[0];
    const int*   wp     = (const int*)d_in[1];
    const float* wscale = (const float*)d_in[2];
    const float* wadd   = (const float*)d_in[3];
    const float* bias   = (const float*)d_in[4];
    float*       out    = (float*)d_out;

    const int M = in_sizes[0] / IN_DIM;   // 8192

    // ws layout: [ wf8 i8 N*K | aq i8 M*K | rowsum f32 M | srow f32 M ]
    char* ws = (char*)d_ws;
    signed char* wf8 = (signed char*)ws;
    const size_t wf_bytes = (size_t)OUT_DIM * IN_DIM;
    int* aq = (int*)(ws + wf_bytes);
    const size_t aq_bytes = (size_t)M * IN_DIM;
    float* rowsum = (float*)(ws + wf_bytes + aq_bytes);
    float* srow   = (float*)(ws + wf_bytes + aq_bytes + (size_t)M * 4);

    const int unpack_blocks = (OUT_DIM * (IN_DIM / 8)) / 256;   // 8192
    unpack_w8<<<unpack_blocks, 256, 0, stream>>>(wp, wf8);

    had_rows_q<<<M, 256, 0, stream>>>(x, aq, rowsum, srow);

    gemm_i8<<<(M / 256) * (OUT_DIM / 256), 512, 0, stream>>>(
        (const signed char*)aq, wf8, wscale, wadd, bias, rowsum, srow, out);
}

// Round 13
// 182.006 us; speedup vs baseline: 1.0887x; 1.0887x over previous
//
#include <hip/hip_runtime.h>
#include <hip/hip_bf16.h>
#include <hip/hip_fp16.h>

#define IN_DIM 4096
#define OUT_DIM 4096
#define HAD_SCALE_F 0.08838834764831845f   // 2^-3.5

typedef int   i32x4 __attribute__((ext_vector_type(4)));
typedef float f32x4 __attribute__((ext_vector_type(4)));

// ---------------------------------------------------------------------------
// Kernel A (verified round-12): FWHT with 16 elems/thread. 8 threads per
// 128-block: strides 1..8 in-register (VALU), strides 16/32/64 via 3
// __shfl_xor masks x 16 elems = 48 shfl/thread. Coalesced 16B/thread I/O.
// Quantization: s_a = rowmax/127, rowsum = s_a*sum(q) (self-consistent).
// ---------------------------------------------------------------------------
__global__ __launch_bounds__(256)
void had_rows_q(const float* __restrict__ x, int* __restrict__ aq,
                float* __restrict__ rowsum, float* __restrict__ srow)
{
    __shared__ float wmx[4];
    __shared__ int   wqs[4];
    const int tid = threadIdx.x;
    const int wv  = tid >> 6;
    const size_t row = blockIdx.x;
    const float* xr = x + row * IN_DIM + tid * 16;

    float e[16];
    #pragma unroll
    for (int v = 0; v < 4; ++v) {
        const float4 f = ((const float4*)xr)[v];
        e[v*4+0] = f.x; e[v*4+1] = f.y; e[v*4+2] = f.z; e[v*4+3] = f.w;
    }

    // FWHT-16 in-register (strides 1,2,4,8)
    #pragma unroll
    for (int s = 1; s < 16; s <<= 1) {
        #pragma unroll
        for (int i = 0; i < 16; ++i) {
            if (!(i & s)) {
                const float u = e[i], w2 = e[i | s];
                e[i]     = u + w2;
                e[i | s] = u - w2;
            }
        }
    }
    // strides 16,32,64 -> lane-xor masks 1,2,4 (8 threads per block, same wave)
    #pragma unroll
    for (int m = 1; m <= 4; m <<= 1) {
        const float sgn = (tid & m) ? -1.0f : 1.0f;
        #pragma unroll
        for (int i = 0; i < 16; ++i) {
            const float p = __shfl_xor(e[i], m, 64);
            e[i] = fmaf(sgn, e[i], p);
        }
    }

    float smax = 0.f;
    #pragma unroll
    for (int i = 0; i < 16; ++i) {
        e[i] *= HAD_SCALE_F;
        smax = fmaxf(smax, fabsf(e[i]));
    }
    #pragma unroll
    for (int off = 32; off > 0; off >>= 1)
        smax = fmaxf(smax, __shfl_xor(smax, off, 64));
    if ((tid & 63) == 0) wmx[wv] = smax;
    __syncthreads();
    const float mx  = fmaxf(fmaxf(wmx[0], wmx[1]), fmaxf(wmx[2], wmx[3]));
    const float inv = (mx > 0.f) ? 127.0f / mx : 0.f;
    const float sa  = mx * (1.0f / 127.0f);

    int qsum = 0;
    int pk[4];
    #pragma unroll
    for (int g2 = 0; g2 < 4; ++g2) {
        const int q0 = (int)rintf(e[g2*4+0] * inv);
        const int q1 = (int)rintf(e[g2*4+1] * inv);
        const int q2 = (int)rintf(e[g2*4+2] * inv);
        const int q3 = (int)rintf(e[g2*4+3] * inv);
        qsum += (q0 + q1) + (q2 + q3);
        pk[g2] = (q0 & 0xFF) | ((q1 & 0xFF) << 8) | ((q2 & 0xFF) << 16) | (q3 << 24);
    }
    *(int4*)&aq[row * (IN_DIM / 4) + tid * 4] = make_int4(pk[0], pk[1], pk[2], pk[3]);

    #pragma unroll
    for (int off = 32; off > 0; off >>= 1) qsum += __shfl_xor(qsum, off, 64);
    if ((tid & 63) == 0) wqs[wv] = qsum;
    __syncthreads();
    if (tid == 0) {
        rowsum[row] = sa * (float)((wqs[0] + wqs[1]) + (wqs[2] + wqs[3]));
        srow[row]   = sa;
    }
}

// ---------------------------------------------------------------------------
// Kernel B: unpack int4 nibbles -> int8 weight matrix [OUT][IN] row-major.
// ---------------------------------------------------------------------------
__global__ __launch_bounds__(256)
void unpack_w8(const int* __restrict__ wp, signed char* __restrict__ wf8)
{
    const int gid = blockIdx.x * 256 + threadIdx.x;
    const int n   = gid >> 9;
    const int k0  = (gid & 511) * 8;
    const int4 p  = *(const int4*)(wp + (size_t)n * (IN_DIM / 2) + (k0 >> 1));
    const unsigned lo = (unsigned)(p.x & 15) | ((unsigned)((p.x >> 4) & 15) << 8)
                      | ((unsigned)(p.y & 15) << 16) | ((unsigned)((p.y >> 4) & 15) << 24);
    const unsigned hi = (unsigned)(p.z & 15) | ((unsigned)((p.z >> 4) & 15) << 8)
                      | ((unsigned)(p.w & 15) << 16) | ((unsigned)((p.w >> 4) & 15) << 24);
    *(uint2*)(wf8 + (size_t)n * IN_DIM + k0) = make_uint2(lo, hi);
}

// ---------------------------------------------------------------------------
// Kernel C: 256x256 int8 GEMM — ROUND-11 VERBATIM (best verified: 136.6 µs,
// MfmaUtil 44%, 0 bank conflicts, mfma_i32_16x16x64_i8). Round 12's 32x32
// port introduced 1.28e7 LDS bank conflicts (h-constant-per-half-wave read
// pattern conflicts despite slot-model predicting free) — reverted.
// 4-window schedule, vm counts W1:2/0 W2:4 W3:2 W4:4, XOR swizzle.
// ---------------------------------------------------------------------------
#define NT (IN_DIM / 128)   // 32 K-regions
#define NI (NT / 2)         // 16 iterations, 2 regions each

#define BAR()        asm volatile("s_barrier" ::: "memory")
#define WAIT_VM(N)   asm volatile("s_waitcnt vmcnt(" #N ")" ::: "memory")

// LDS: A0 @ 0, B0 @ 32768, A1 @ 65536, B1 @ 98304 (each 32 KiB = 256 rows x 128 B)
#define STAGE_A(p, R, kt) __builtin_amdgcn_global_load_lds( \
    (const __attribute__((address_space(1))) void*)(sA + (((size_t)(R)) << 18) + (((size_t)((kt) & 31)) << 7)), \
    (__attribute__((address_space(3))) void*)(smem + (p) * 65536 + (R) * 8192 + dstA), 16, 0, 0)
#define STAGE_B(p, R, kt) __builtin_amdgcn_global_load_lds( \
    (const __attribute__((address_space(1))) void*)(sB + (((size_t)(R)) << 18) + (((size_t)((kt) & 31)) << 7)), \
    (__attribute__((address_space(3))) void*)(smem + (p) * 65536 + (R) * 8192 + dstB), 16, 0, 0)

#define LDA(p, mq, mi, kb) (*(const i32x4*)(smem + (p)*65536 + (mq)*8192 + (mi)*2048 + aOffK[kb]))
#define LDB(p, nq, ni, kb) (*(const i32x4*)(smem + (p)*65536 + (nq)*4096 + (ni)*2048 + bOffK[kb]))

#define LOAD_A_TO(dst, p, mq) do { \
    _Pragma("unroll") for (int mi = 0; mi < 4; ++mi) { \
        dst[mi][0] = LDA(p, mq, mi, 0); \
        dst[mi][1] = LDA(p, mq, mi, 1); \
    } } while (0)

#define LOAD_B(p, nq) do { \
    _Pragma("unroll") for (int ni = 0; ni < 2; ++ni) { \
        bfr[(nq)*2+ni][0] = LDB(p, nq, ni, 0); \
        bfr[(nq)*2+ni][1] = LDB(p, nq, ni, 1); \
    } } while (0)

#define MFMA_Q(abuf, mq, nq) do { \
    __builtin_amdgcn_s_setprio(1); \
    _Pragma("unroll") for (int mi = 0; mi < 4; ++mi) \
    _Pragma("unroll") for (int ni = 0; ni < 2; ++ni) \
    _Pragma("unroll") for (int kb = 0; kb < 2; ++kb) \
        acc[(mq)*4+mi][(nq)*2+ni] = __builtin_amdgcn_mfma_i32_16x16x64_i8( \
            abuf[mi][kb], bfr[(nq)*2+ni][kb], acc[(mq)*4+mi][(nq)*2+ni], 0, 0, 0); \
    __builtin_amdgcn_s_setprio(0); \
} while (0)

__global__ __launch_bounds__(512, 2)
void gemm_i8(const signed char* __restrict__ Aq, const signed char* __restrict__ Bw,
             const float* __restrict__ wscale, const float* __restrict__ wadd,
             const float* __restrict__ bias, const float* __restrict__ rowsum,
             const float* __restrict__ srow, float* __restrict__ out)
{
    __shared__ char smem[131072];

    const int tid  = threadIdx.x;
    const int lane = tid & 63;
    const int w    = tid >> 6;     // wave 0..7
    const int wm   = w >> 2;       // 0..1
    const int wn   = w & 3;        // 0..3

    // XCD-aware bijective swizzle: 512 wgs, 8 XCDs, 64 per XCD
    const int bid = blockIdx.x;
    const int wg  = (bid & 7) * 64 + (bid >> 3);
    const int m0  = (wg >> 4) * 256;   // M/256 = 32
    const int n0  = (wg & 15) * 256;   // N/256 = 16

    // ---- staging addresses (pre-swizzled source, linear LDS dest) ----
    const int rt = tid >> 3;
    const int ct = (tid & 7) ^ (rt & 7);
    const signed char* sA = Aq + (size_t)(m0 + rt) * IN_DIM + ct * 16;
    const signed char* sB = Bw + (size_t)(n0 + rt) * IN_DIM + ct * 16;
    const int dstA = w * 1024;
    const int dstB = 32768 + w * 1024;

    // ---- fragment read offsets (swizzled) ----
    const int l15 = lane & 15, g = lane >> 4, l7 = lane & 7;
    const int s0 = (g ^ l7) << 4;
    int aOffK[2], bOffK[2];
    aOffK[0] = (wm * 128 + l15) * 128 + s0;
    aOffK[1] = (wm * 128 + l15) * 128 + (s0 ^ 64);
    bOffK[0] = 32768 + (wn * 64 + l15) * 128 + s0;
    bOffK[1] = 32768 + (wn * 64 + l15) * 128 + (s0 ^ 64);

    i32x4 afrA[4][2], afrB[4][2], bfr[4][2];
    i32x4 acc[8][4] = {};

    // ---- prologue: region0 -> buf0, region1 -> buf1 ----
    #pragma unroll
    for (int R = 0; R < 4; ++R) { STAGE_A(0, R, 0); STAGE_B(0, R, 0); }
    #pragma unroll
    for (int R = 0; R < 4; ++R) { STAGE_A(1, R, 1); STAGE_B(1, R, 1); }
    WAIT_VM(8);
    BAR();
    LOAD_B(0, 0);
    LOAD_A_TO(afrA, 0, 0);

    #pragma unroll 1
    for (int it = 0; it < NI; ++it) {
        const int kt1 = 2 * it + 1;
        const int kt2 = (2 * it + 2) & (NT - 1);
        const int kt3 = (2 * it + 3) & (NT - 1);

        // ---- W1: MFMA b0 quads(0,*) | read b0 nq1,h1 | stage b1 {Br2,r3, Ar1,r3}(kt1)
        LOAD_B(0, 1);
        if (it) { STAGE_B(1, 2, kt1); STAGE_B(1, 3, kt1);
                  STAGE_A(1, 1, kt1); STAGE_A(1, 3, kt1); }
        MFMA_Q(afrA, 0, 0);
        LOAD_A_TO(afrB, 0, 1);
        MFMA_Q(afrA, 0, 1);
        if (it) { WAIT_VM(2); } else { WAIT_VM(0); }
        BAR();

        // ---- W2: MFMA b0 quads(1,*) | read b1 nq0,h0 | stage b0 {Br0,r1, Ar0,r2}(kt2)
        STAGE_B(0, 0, kt2); STAGE_B(0, 1, kt2);
        MFMA_Q(afrB, 1, 0);
        LOAD_B(1, 0);
        LOAD_A_TO(afrA, 1, 0);
        STAGE_A(0, 0, kt2); STAGE_A(0, 2, kt2);
        MFMA_Q(afrB, 1, 1);
        WAIT_VM(4);
        BAR();

        // ---- W3: MFMA b1 quads(0,*) | read b1 nq1,h1 | stage b0 {Br2,r3, Ar1,r3}(kt2)
        STAGE_B(0, 2, kt2); STAGE_B(0, 3, kt2);
        MFMA_Q(afrA, 0, 0);
        LOAD_B(1, 1);
        LOAD_A_TO(afrB, 1, 1);
        STAGE_A(0, 1, kt2); STAGE_A(0, 3, kt2);
        MFMA_Q(afrA, 0, 1);
        WAIT_VM(2);
        BAR();

        // ---- W4: MFMA b1 quads(1,*) | read b0' nq0,h0 | stage b1 {Br0,r1, Ar0,r2}(kt3)
        STAGE_B(1, 0, kt3); STAGE_B(1, 1, kt3);
        MFMA_Q(afrB, 1, 0);
        LOAD_B(0, 0);
        LOAD_A_TO(afrA, 0, 0);
        STAGE_A(1, 0, kt3); STAGE_A(1, 2, kt3);
        MFMA_Q(afrB, 1, 1);
        WAIT_VM(4);
        BAR();
    }

    // ---- epilogue: y = srow[m]*wscale[n]*acc + wadd[n]*rowsum[m] + bias[n] ----
    #pragma unroll
    for (int n = 0; n < 4; ++n) {
        const int col = n0 + wn * 64 + n * 16 + l15;
        const float sc = wscale[col];
        const float ad = wadd[col];
        const float bi = bias[col];
        #pragma unroll
        for (int m = 0; m < 8; ++m) {
            const int row = m0 + wm * 128 + m * 16 + g * 4;
            const float4 rs4 = *(const float4*)&rowsum[row];
            const float4 sr4 = *(const float4*)&srow[row];
            #pragma unroll
            for (int j = 0; j < 4; ++j) {
                const float rs = (j == 0) ? rs4.x : (j == 1) ? rs4.y : (j == 2) ? rs4.z : rs4.w;
                const float sr = (j == 0) ? sr4.x : (j == 1) ? sr4.y : (j == 2) ? sr4.z : sr4.w;
                out[(size_t)(row + j) * OUT_DIM + col] =
                    (float)acc[m][n][j] * (sc * sr) + ad * rs + bi;
            }
        }
    }
}

// ---------------------------------------------------------------------------
extern "C" void kernel_launch(void* const* d_in, const int* in_sizes, int n_in,
                              void* d_out, int out_size, void* d_ws, size_t ws_size,
                              hipStream_t stream)
{
    const float* x      = (const float*)d_in[0];
    const int*   wp     = (const int*)d_in[1];
    const float* wscale = (const float*)d_in[2];
    const float* wadd   = (const float*)d_in[3];
    const float* bias   = (const float*)d_in[4];
    float*       out    = (float*)d_out;

    const int M = in_sizes[0] / IN_DIM;   // 8192

    // ws layout: [ wf8 i8 N*K | aq i8 M*K | rowsum f32 M | srow f32 M ]
    char* ws = (char*)d_ws;
    signed char* wf8 = (signed char*)ws;
    const size_t wf_bytes = (size_t)OUT_DIM * IN_DIM;
    int* aq = (int*)(ws + wf_bytes);
    const size_t aq_bytes = (size_t)M * IN_DIM;
    float* rowsum = (float*)(ws + wf_bytes + aq_bytes);
    float* srow   = (float*)(ws + wf_bytes + aq_bytes + (size_t)M * 4);

    const int unpack_blocks = (OUT_DIM * (IN_DIM / 8)) / 256;   // 8192
    unpack_w8<<<unpack_blocks, 256, 0, stream>>>(wp, wf8);

    had_rows_q<<<M, 256, 0, stream>>>(x, aq, rowsum, srow);

    gemm_i8<<<(M / 256) * (OUT_DIM / 256), 512, 0, stream>>>(
        (const signed char*)aq, wf8, wscale, wadd, bias, rowsum, srow, out);
}

// Round 14
// 181.327 us; speedup vs baseline: 1.0927x; 1.0037x over previous
//
#include <hip/hip_runtime.h>
#include <hip/hip_bf16.h>
#include <hip/hip_fp16.h>

#define IN_DIM 4096
#define OUT_DIM 4096
#define HAD_SCALE_F 0.08838834764831845f   // 2^-3.5

typedef int   i32x4 __attribute__((ext_vector_type(4)));
typedef float f32x4 __attribute__((ext_vector_type(4)));

// ---------------------------------------------------------------------------
// Kernel A (verified round-12/13): FWHT with 16 elems/thread. 8 threads per
// 128-block: strides 1..8 in-register (VALU), strides 16/32/64 via 3
// __shfl_xor masks x 16 elems = 48 shfl/thread. Coalesced 16B/thread I/O.
// Quantization: s_a = rowmax/127, rowsum = s_a*sum(q) (self-consistent).
// ---------------------------------------------------------------------------
__global__ __launch_bounds__(256)
void had_rows_q(const float* __restrict__ x, int* __restrict__ aq,
                float* __restrict__ rowsum, float* __restrict__ srow)
{
    __shared__ float wmx[4];
    __shared__ int   wqs[4];
    const int tid = threadIdx.x;
    const int wv  = tid >> 6;
    const size_t row = blockIdx.x;
    const float* xr = x + row * IN_DIM + tid * 16;

    float e[16];
    #pragma unroll
    for (int v = 0; v < 4; ++v) {
        const float4 f = ((const float4*)xr)[v];
        e[v*4+0] = f.x; e[v*4+1] = f.y; e[v*4+2] = f.z; e[v*4+3] = f.w;
    }

    // FWHT-16 in-register (strides 1,2,4,8)
    #pragma unroll
    for (int s = 1; s < 16; s <<= 1) {
        #pragma unroll
        for (int i = 0; i < 16; ++i) {
            if (!(i & s)) {
                const float u = e[i], w2 = e[i | s];
                e[i]     = u + w2;
                e[i | s] = u - w2;
            }
        }
    }
    // strides 16,32,64 -> lane-xor masks 1,2,4 (8 threads per block, same wave)
    #pragma unroll
    for (int m = 1; m <= 4; m <<= 1) {
        const float sgn = (tid & m) ? -1.0f : 1.0f;
        #pragma unroll
        for (int i = 0; i < 16; ++i) {
            const float p = __shfl_xor(e[i], m, 64);
            e[i] = fmaf(sgn, e[i], p);
        }
    }

    float smax = 0.f;
    #pragma unroll
    for (int i = 0; i < 16; ++i) {
        e[i] *= HAD_SCALE_F;
        smax = fmaxf(smax, fabsf(e[i]));
    }
    #pragma unroll
    for (int off = 32; off > 0; off >>= 1)
        smax = fmaxf(smax, __shfl_xor(smax, off, 64));
    if ((tid & 63) == 0) wmx[wv] = smax;
    __syncthreads();
    const float mx  = fmaxf(fmaxf(wmx[0], wmx[1]), fmaxf(wmx[2], wmx[3]));
    const float inv = (mx > 0.f) ? 127.0f / mx : 0.f;
    const float sa  = mx * (1.0f / 127.0f);

    int qsum = 0;
    int pk[4];
    #pragma unroll
    for (int g2 = 0; g2 < 4; ++g2) {
        const int q0 = (int)rintf(e[g2*4+0] * inv);
        const int q1 = (int)rintf(e[g2*4+1] * inv);
        const int q2 = (int)rintf(e[g2*4+2] * inv);
        const int q3 = (int)rintf(e[g2*4+3] * inv);
        qsum += (q0 + q1) + (q2 + q3);
        pk[g2] = (q0 & 0xFF) | ((q1 & 0xFF) << 8) | ((q2 & 0xFF) << 16) | (q3 << 24);
    }
    *(int4*)&aq[row * (IN_DIM / 4) + tid * 4] = make_int4(pk[0], pk[1], pk[2], pk[3]);

    #pragma unroll
    for (int off = 32; off > 0; off >>= 1) qsum += __shfl_xor(qsum, off, 64);
    if ((tid & 63) == 0) wqs[wv] = qsum;
    __syncthreads();
    if (tid == 0) {
        rowsum[row] = sa * (float)((wqs[0] + wqs[1]) + (wqs[2] + wqs[3]));
        srow[row]   = sa;
    }
}

// ---------------------------------------------------------------------------
// Kernel B: unpack int4 nibbles -> int8 weight matrix [OUT][IN] row-major.
// ---------------------------------------------------------------------------
__global__ __launch_bounds__(256)
void unpack_w8(const int* __restrict__ wp, signed char* __restrict__ wf8)
{
    const int gid = blockIdx.x * 256 + threadIdx.x;
    const int n   = gid >> 9;
    const int k0  = (gid & 511) * 8;
    const int4 p  = *(const int4*)(wp + (size_t)n * (IN_DIM / 2) + (k0 >> 1));
    const unsigned lo = (unsigned)(p.x & 15) | ((unsigned)((p.x >> 4) & 15) << 8)
                      | ((unsigned)(p.y & 15) << 16) | ((unsigned)((p.y >> 4) & 15) << 24);
    const unsigned hi = (unsigned)(p.z & 15) | ((unsigned)((p.z >> 4) & 15) << 8)
                      | ((unsigned)(p.w & 15) << 16) | ((unsigned)((p.w >> 4) & 15) << 24);
    *(uint2*)(wf8 + (size_t)n * IN_DIM + k0) = make_uint2(lo, hi);
}

// ---------------------------------------------------------------------------
// Kernel C: 256x256 int8 GEMM, R8/R11 4-window schedule. ROUND-14 CHANGE:
// MFMA_Q loop order kb-OUTER. With kb innermost, every 2nd MFMA accumulated
// into the same acc frag as its predecessor (back-to-back dependent pair,
// ~20cy issue stall x 64 pairs/region ~= the measured 5085-4122 residual).
// kb-outer puts dependent MFMAs 8 issue-slots apart -> wave issues all 16
// without stalling and races ahead into the next window's ds_reads, letting
// the matrix pipe drain under the LDS burst (MFMA is issue-and-continue).
// Integer accumulation commutes exactly -> bit-identical output.
// Everything else verbatim from R13 (135.9 us, 0 conflicts, verified 3x).
// ---------------------------------------------------------------------------
#define NT (IN_DIM / 128)   // 32 K-regions
#define NI (NT / 2)         // 16 iterations, 2 regions each

#define BAR()        asm volatile("s_barrier" ::: "memory")
#define WAIT_VM(N)   asm volatile("s_waitcnt vmcnt(" #N ")" ::: "memory")

// LDS: A0 @ 0, B0 @ 32768, A1 @ 65536, B1 @ 98304 (each 32 KiB = 256 rows x 128 B)
#define STAGE_A(p, R, kt) __builtin_amdgcn_global_load_lds( \
    (const __attribute__((address_space(1))) void*)(sA + (((size_t)(R)) << 18) + (((size_t)((kt) & 31)) << 7)), \
    (__attribute__((address_space(3))) void*)(smem + (p) * 65536 + (R) * 8192 + dstA), 16, 0, 0)
#define STAGE_B(p, R, kt) __builtin_amdgcn_global_load_lds( \
    (const __attribute__((address_space(1))) void*)(sB + (((size_t)(R)) << 18) + (((size_t)((kt) & 31)) << 7)), \
    (__attribute__((address_space(3))) void*)(smem + (p) * 65536 + (R) * 8192 + dstB), 16, 0, 0)

#define LDA(p, mq, mi, kb) (*(const i32x4*)(smem + (p)*65536 + (mq)*8192 + (mi)*2048 + aOffK[kb]))
#define LDB(p, nq, ni, kb) (*(const i32x4*)(smem + (p)*65536 + (nq)*4096 + (ni)*2048 + bOffK[kb]))

#define LOAD_A_TO(dst, p, mq) do { \
    _Pragma("unroll") for (int mi = 0; mi < 4; ++mi) { \
        dst[mi][0] = LDA(p, mq, mi, 0); \
        dst[mi][1] = LDA(p, mq, mi, 1); \
    } } while (0)

#define LOAD_B(p, nq) do { \
    _Pragma("unroll") for (int ni = 0; ni < 2; ++ni) { \
        bfr[(nq)*2+ni][0] = LDB(p, nq, ni, 0); \
        bfr[(nq)*2+ni][1] = LDB(p, nq, ni, 1); \
    } } while (0)

// kb-outer: dependent (same-acc) MFMAs are 8 apart in issue order
#define MFMA_Q(abuf, mq, nq) do { \
    __builtin_amdgcn_s_setprio(1); \
    _Pragma("unroll") for (int kb = 0; kb < 2; ++kb) \
    _Pragma("unroll") for (int mi = 0; mi < 4; ++mi) \
    _Pragma("unroll") for (int ni = 0; ni < 2; ++ni) \
        acc[(mq)*4+mi][(nq)*2+ni] = __builtin_amdgcn_mfma_i32_16x16x64_i8( \
            abuf[mi][kb], bfr[(nq)*2+ni][kb], acc[(mq)*4+mi][(nq)*2+ni], 0, 0, 0); \
    __builtin_amdgcn_s_setprio(0); \
} while (0)

__global__ __launch_bounds__(512, 2)
void gemm_i8(const signed char* __restrict__ Aq, const signed char* __restrict__ Bw,
             const float* __restrict__ wscale, const float* __restrict__ wadd,
             const float* __restrict__ bias, const float* __restrict__ rowsum,
             const float* __restrict__ srow, float* __restrict__ out)
{
    __shared__ char smem[131072];

    const int tid  = threadIdx.x;
    const int lane = tid & 63;
    const int w    = tid >> 6;     // wave 0..7
    const int wm   = w >> 2;       // 0..1
    const int wn   = w & 3;        // 0..3

    // XCD-aware bijective swizzle: 512 wgs, 8 XCDs, 64 per XCD
    const int bid = blockIdx.x;
    const int wg  = (bid & 7) * 64 + (bid >> 3);
    const int m0  = (wg >> 4) * 256;   // M/256 = 32
    const int n0  = (wg & 15) * 256;   // N/256 = 16

    // ---- staging addresses (pre-swizzled source, linear LDS dest) ----
    const int rt = tid >> 3;
    const int ct = (tid & 7) ^ (rt & 7);
    const signed char* sA = Aq + (size_t)(m0 + rt) * IN_DIM + ct * 16;
    const signed char* sB = Bw + (size_t)(n0 + rt) * IN_DIM + ct * 16;
    const int dstA = w * 1024;
    const int dstB = 32768 + w * 1024;

    // ---- fragment read offsets (swizzled) ----
    const int l15 = lane & 15, g = lane >> 4, l7 = lane & 7;
    const int s0 = (g ^ l7) << 4;
    int aOffK[2], bOffK[2];
    aOffK[0] = (wm * 128 + l15) * 128 + s0;
    aOffK[1] = (wm * 128 + l15) * 128 + (s0 ^ 64);
    bOffK[0] = 32768 + (wn * 64 + l15) * 128 + s0;
    bOffK[1] = 32768 + (wn * 64 + l15) * 128 + (s0 ^ 64);

    i32x4 afrA[4][2], afrB[4][2], bfr[4][2];
    i32x4 acc[8][4] = {};

    // ---- prologue: region0 -> buf0, region1 -> buf1 ----
    #pragma unroll
    for (int R = 0; R < 4; ++R) { STAGE_A(0, R, 0); STAGE_B(0, R, 0); }
    #pragma unroll
    for (int R = 0; R < 4; ++R) { STAGE_A(1, R, 1); STAGE_B(1, R, 1); }
    WAIT_VM(8);
    BAR();
    LOAD_B(0, 0);
    LOAD_A_TO(afrA, 0, 0);

    #pragma unroll 1
    for (int it = 0; it < NI; ++it) {
        const int kt1 = 2 * it + 1;
        const int kt2 = (2 * it + 2) & (NT - 1);
        const int kt3 = (2 * it + 3) & (NT - 1);

        // ---- W1: MFMA b0 quads(0,*) | read b0 nq1,h1 | stage b1 {Br2,r3, Ar1,r3}(kt1)
        LOAD_B(0, 1);
        if (it) { STAGE_B(1, 2, kt1); STAGE_B(1, 3, kt1);
                  STAGE_A(1, 1, kt1); STAGE_A(1, 3, kt1); }
        MFMA_Q(afrA, 0, 0);
        LOAD_A_TO(afrB, 0, 1);
        MFMA_Q(afrA, 0, 1);
        if (it) { WAIT_VM(2); } else { WAIT_VM(0); }
        BAR();

        // ---- W2: MFMA b0 quads(1,*) | read b1 nq0,h0 | stage b0 {Br0,r1, Ar0,r2}(kt2)
        STAGE_B(0, 0, kt2); STAGE_B(0, 1, kt2);
        MFMA_Q(afrB, 1, 0);
        LOAD_B(1, 0);
        LOAD_A_TO(afrA, 1, 0);
        STAGE_A(0, 0, kt2); STAGE_A(0, 2, kt2);
        MFMA_Q(afrB, 1, 1);
        WAIT_VM(4);
        BAR();

        // ---- W3: MFMA b1 quads(0,*) | read b1 nq1,h1 | stage b0 {Br2,r3, Ar1,r3}(kt2)
        STAGE_B(0, 2, kt2); STAGE_B(0, 3, kt2);
        MFMA_Q(afrA, 0, 0);
        LOAD_B(1, 1);
        LOAD_A_TO(afrB, 1, 1);
        STAGE_A(0, 1, kt2); STAGE_A(0, 3, kt2);
        MFMA_Q(afrA, 0, 1);
        WAIT_VM(2);
        BAR();

        // ---- W4: MFMA b1 quads(1,*) | read b0' nq0,h0 | stage b1 {Br0,r1, Ar0,r2}(kt3)
        STAGE_B(1, 0, kt3); STAGE_B(1, 1, kt3);
        MFMA_Q(afrB, 1, 0);
        LOAD_B(0, 0);
        LOAD_A_TO(afrA, 0, 0);
        STAGE_A(1, 0, kt3); STAGE_A(1, 2, kt3);
        MFMA_Q(afrB, 1, 1);
        WAIT_VM(4);
        BAR();
    }

    // ---- epilogue: y = srow[m]*wscale[n]*acc + wadd[n]*rowsum[m] + bias[n] ----
    #pragma unroll
    for (int n = 0; n < 4; ++n) {
        const int col = n0 + wn * 64 + n * 16 + l15;
        const float sc = wscale[col];
        const float ad = wadd[col];
        const float bi = bias[col];
        #pragma unroll
        for (int m = 0; m < 8; ++m) {
            const int row = m0 + wm * 128 + m * 16 + g * 4;
            const float4 rs4 = *(const float4*)&rowsum[row];
            const float4 sr4 = *(const float4*)&srow[row];
            #pragma unroll
            for (int j = 0; j < 4; ++j) {
                const float rs = (j == 0) ? rs4.x : (j == 1) ? rs4.y : (j == 2) ? rs4.z : rs4.w;
                const float sr = (j == 0) ? sr4.x : (j == 1) ? sr4.y : (j == 2) ? sr4.z : sr4.w;
                out[(size_t)(row + j) * OUT_DIM + col] =
                    (float)acc[m][n][j] * (sc * sr) + ad * rs + bi;
            }
        }
    }
}

// ---------------------------------------------------------------------------
extern "C" void kernel_launch(void* const* d_in, const int* in_sizes, int n_in,
                              void* d_out, int out_size, void* d_ws, size_t ws_size,
                              hipStream_t stream)
{
    const float* x      = (const float*)d_in[0];
    const int*   wp     = (const int*)d_in[1];
    const float* wscale = (const float*)d_in[2];
    const float* wadd   = (const float*)d_in[3];
    const float* bias   = (const float*)d_in[4];
    float*       out    = (float*)d_out;

    const int M = in_sizes[0] / IN_DIM;   // 8192

    // ws layout: [ wf8 i8 N*K | aq i8 M*K | rowsum f32 M | srow f32 M ]
    char* ws = (char*)d_ws;
    signed char* wf8 = (signed char*)ws;
    const size_t wf_bytes = (size_t)OUT_DIM * IN_DIM;
    int* aq = (int*)(ws + wf_bytes);
    const size_t aq_bytes = (size_t)M * IN_DIM;
    float* rowsum = (float*)(ws + wf_bytes + aq_bytes);
    float* srow   = (float*)(ws + wf_bytes + aq_bytes + (size_t)M * 4);

    const int unpack_blocks = (OUT_DIM * (IN_DIM / 8)) / 256;   // 8192
    unpack_w8<<<unpack_blocks, 256, 0, stream>>>(wp, wf8);

    had_rows_q<<<M, 256, 0, stream>>>(x, aq, rowsum, srow);

    gemm_i8<<<(M / 256) * (OUT_DIM / 256), 512, 0, stream>>>(
        (const signed char*)aq, wf8, wscale, wadd, bias, rowsum, srow, out);
}

// Round 15
// 175.058 us; speedup vs baseline: 1.1319x; 1.0358x over previous
//
#include <hip/hip_runtime.h>
#include <hip/hip_bf16.h>
#include <hip/hip_fp16.h>

#define IN_DIM 4096
#define OUT_DIM 4096
#define HAD_SCALE_F 0.08838834764831845f   // 2^-3.5

typedef int   i32x4 __attribute__((ext_vector_type(4)));
typedef float f32x4 __attribute__((ext_vector_type(4)));

// ---------------------------------------------------------------------------
// Kernel A (verified R12/R13): wave/in-register FWHT, 16 elems/thread,
// s_a = rowmax/127, rowsum = s_a*sum(q) (self-consistent decomposition).
// ---------------------------------------------------------------------------
__global__ __launch_bounds__(256)
void had_rows_q(const float* __restrict__ x, int* __restrict__ aq,
                float* __restrict__ rowsum, float* __restrict__ srow)
{
    __shared__ float wmx[4];
    __shared__ int   wqs[4];
    const int tid = threadIdx.x;
    const int wv  = tid >> 6;
    const size_t row = blockIdx.x;
    const float* xr = x + row * IN_DIM + tid * 16;

    float e[16];
    #pragma unroll
    for (int v = 0; v < 4; ++v) {
        const float4 f = ((const float4*)xr)[v];
        e[v*4+0] = f.x; e[v*4+1] = f.y; e[v*4+2] = f.z; e[v*4+3] = f.w;
    }

    #pragma unroll
    for (int s = 1; s < 16; s <<= 1) {
        #pragma unroll
        for (int i = 0; i < 16; ++i) {
            if (!(i & s)) {
                const float u = e[i], w2 = e[i | s];
                e[i]     = u + w2;
                e[i | s] = u - w2;
            }
        }
    }
    #pragma unroll
    for (int m = 1; m <= 4; m <<= 1) {
        const float sgn = (tid & m) ? -1.0f : 1.0f;
        #pragma unroll
        for (int i = 0; i < 16; ++i) {
            const float p = __shfl_xor(e[i], m, 64);
            e[i] = fmaf(sgn, e[i], p);
        }
    }

    float smax = 0.f;
    #pragma unroll
    for (int i = 0; i < 16; ++i) {
        e[i] *= HAD_SCALE_F;
        smax = fmaxf(smax, fabsf(e[i]));
    }
    #pragma unroll
    for (int off = 32; off > 0; off >>= 1)
        smax = fmaxf(smax, __shfl_xor(smax, off, 64));
    if ((tid & 63) == 0) wmx[wv] = smax;
    __syncthreads();
    const float mx  = fmaxf(fmaxf(wmx[0], wmx[1]), fmaxf(wmx[2], wmx[3]));
    const float inv = (mx > 0.f) ? 127.0f / mx : 0.f;
    const float sa  = mx * (1.0f / 127.0f);

    int qsum = 0;
    int pk[4];
    #pragma unroll
    for (int g2 = 0; g2 < 4; ++g2) {
        const int q0 = (int)rintf(e[g2*4+0] * inv);
        const int q1 = (int)rintf(e[g2*4+1] * inv);
        const int q2 = (int)rintf(e[g2*4+2] * inv);
        const int q3 = (int)rintf(e[g2*4+3] * inv);
        qsum += (q0 + q1) + (q2 + q3);
        pk[g2] = (q0 & 0xFF) | ((q1 & 0xFF) << 8) | ((q2 & 0xFF) << 16) | (q3 << 24);
    }
    *(int4*)&aq[row * (IN_DIM / 4) + tid * 4] = make_int4(pk[0], pk[1], pk[2], pk[3]);

    #pragma unroll
    for (int off = 32; off > 0; off >>= 1) qsum += __shfl_xor(qsum, off, 64);
    if ((tid & 63) == 0) wqs[wv] = qsum;
    __syncthreads();
    if (tid == 0) {
        rowsum[row] = sa * (float)((wqs[0] + wqs[1]) + (wqs[2] + wqs[3]));
        srow[row]   = sa;
    }
}

// ---------------------------------------------------------------------------
// Kernel B (round-15): repack int4 weights into interleaved-nibble chunks.
// Layout: wf4[n][kt][c] = 16 bytes, byte jj = (w[n][kt*128+64+c*16+jj]<<4)
//                                          |  w[n][kt*128+   c*16+jj]
// so in the GEMM, packed & 0x0F0F0F0F = kb0 fragment bytes and
// (packed>>4) & 0x0F0F0F0F = kb1 fragment bytes (2 VALU per dword).
// ---------------------------------------------------------------------------
__global__ __launch_bounds__(256)
void unpack_w4i(const int* __restrict__ wp, unsigned char* __restrict__ wf4)
{
    const int gid = blockIdx.x * 256 + threadIdx.x;   // 4096*32*4 = 524288
    const int c   = gid & 3;
    const int kt  = (gid >> 2) & 31;
    const int n   = gid >> 7;
    const int kbase = kt * 128 + c * 16;
    const int* row = wp + (size_t)n * (IN_DIM / 2) + (kbase >> 1);
    const int4 plo0 = *(const int4*)(row);        // k jj 0..7  (2 nibbles/int)
    const int4 plo1 = *(const int4*)(row + 4);    // k jj 8..15
    const int4 phi0 = *(const int4*)(row + 32);   // k+64 jj 0..7
    const int4 phi1 = *(const int4*)(row + 36);   // k+64 jj 8..15

    #define MKD(lo, hi, lo2, hi2) \
        ( (unsigned)(((lo) & 15) | (((hi) & 15) << 4)) \
        | ((unsigned)((((lo) >> 4) & 15) | ((((hi) >> 4) & 15) << 4)) << 8) \
        | ((unsigned)(((lo2) & 15) | (((hi2) & 15) << 4)) << 16) \
        | ((unsigned)((((lo2) >> 4) & 15) | ((((hi2) >> 4) & 15) << 4)) << 24) )

    uint4 o;
    o.x = MKD(plo0.x, phi0.x, plo0.y, phi0.y);
    o.y = MKD(plo0.z, phi0.z, plo0.w, phi0.w);
    o.z = MKD(plo1.x, phi1.x, plo1.y, phi1.y);
    o.w = MKD(plo1.z, phi1.z, plo1.w, phi1.w);
    #undef MKD
    *(uint4*)(wf4 + (size_t)gid * 16) = o;
}

// ---------------------------------------------------------------------------
// Kernel C (round-15): 128x256 block, 4 waves (wave tile 128x64),
// 2 CO-RESIDENT BLOCKS/CU (LDS 48 KiB, VGPR ~233). A: i8 double-buffer
// (2x16 KiB, verified 128B-row XOR swizzle). B: packed-int4 single buffer
// (16 KiB, 64B rows, 4-slot XOR swizzle), unpacked in-register (2 VALU/dword).
// Region kt: {STAGE_A(kt+1); read B+A_h0; lgkmcnt(0); BAR; STAGE_B(kt+1);
//  MFMA h0; read A_h1; MFMA h1; vmcnt(0); BAR}. B restage is strictly after
// the all-waves-read barrier; B(kt+1) stage latency hides under 64 MFMAs.
// Intra-block serialization is covered by the co-resident block (m97/m114
// mechanism) — the first occupancy-based attack after 6 scheduling nulls.
// ---------------------------------------------------------------------------
#define NT 32   // K-regions of 128

#define BAR()        asm volatile("s_barrier" ::: "memory")
#define WAIT_VM(N)   asm volatile("s_waitcnt vmcnt(" #N ")" ::: "memory")
#define WAIT_LGKM0() asm volatile("s_waitcnt lgkmcnt(0)" ::: "memory")

// LDS: A0 @ 0 (16K), A1 @ 16384, B @ 32768 (16K)
#define STAGE_A(buf, kt) do { \
    _Pragma("unroll") for (int R = 0; R < 4; ++R) \
        __builtin_amdgcn_global_load_lds( \
            (const __attribute__((address_space(1))) void*)(sA + ((size_t)R << 17) + (((kt) & 31) << 7)), \
            (__attribute__((address_space(3))) void*)(smem + (buf) * 16384 + R * 4096 + wv * 1024), 16, 0, 0); \
    } while (0)
#define STAGE_B(kt) do { \
    _Pragma("unroll") for (int R = 0; R < 4; ++R) \
        __builtin_amdgcn_global_load_lds( \
            (const __attribute__((address_space(1))) void*)(sB + ((size_t)R << 17) + (((kt) & 31) << 6)), \
            (__attribute__((address_space(3))) void*)(smem + 32768 + R * 4096 + wv * 1024), 16, 0, 0); \
    } while (0)

__global__ __launch_bounds__(256, 2)
void gemm_i8(const signed char* __restrict__ Aq, const unsigned char* __restrict__ Bw4,
             const float* __restrict__ wscale, const float* __restrict__ wadd,
             const float* __restrict__ bias, const float* __restrict__ rowsum,
             const float* __restrict__ srow, float* __restrict__ out)
{
    __shared__ char smem[49152];

    const int tid  = threadIdx.x;
    const int lane = tid & 63;
    const int wv   = tid >> 6;    // wave 0..3 = output col quarter (wn)

    // XCD swizzle: 1024 wgs = 8 XCDs x 128
    const int bid = blockIdx.x;
    const int wg  = (bid & 7) * 128 + (bid >> 3);
    const int m0  = (wg >> 4) * 128;   // 64 m-tiles
    const int n0  = (wg & 15) * 256;   // 16 n-tiles

    // ---- A staging (verified pattern): round R = rows R*32..R*32+31 ----
    const int art = tid >> 3;                       // row 0..31 within round
    const int act = (tid & 7) ^ (art & 7);          // pre-swizzled source chunk
    const signed char* sA = Aq + (size_t)(m0 + art) * IN_DIM + act * 16;

    // ---- B staging: 64B rows, round R = rows R*64..R*64+63 ----
    const int brt = tid >> 2;                       // row 0..63 within round
    const int bct = (tid & 3) ^ (brt & 3);
    const unsigned char* sB = Bw4 + (size_t)(n0 + brt) * 2048 + bct * 16;

    // ---- fragment read offsets ----
    const int l15 = lane & 15, g = lane >> 4, l7 = lane & 7, l3 = lane & 3;
    const int aOff = l15 * 128 + ((g ^ l7) << 4);            // + mi*2048, ^ kb*64
    const int bOff = 32768 + (wv * 64 + l15) * 64 + ((g ^ l3) << 4);  // + ni*1024

    i32x4 afr[4][2], b0[4], b1[4];
    i32x4 acc[8][4] = {};

    // ---- prologue ----
    STAGE_A(0, 0);
    STAGE_B(0);
    WAIT_VM(0);
    BAR();

    #pragma unroll 1
    for (int kt = 0; kt < NT; ++kt) {
        const int cur = kt & 1;

        // stage next A tile into the other buffer
        STAGE_A(cur ^ 1, kt + 1);

        // read B packed (4 b128) + A rows 0..63 (8 b128)
        i32x4 bp[4];
        #pragma unroll
        for (int ni = 0; ni < 4; ++ni)
            bp[ni] = *(const i32x4*)(smem + bOff + ni * 1024);
        #pragma unroll
        for (int mi = 0; mi < 4; ++mi) {
            afr[mi][0] = *(const i32x4*)(smem + cur * 16384 + mi * 2048 + aOff);
            afr[mi][1] = *(const i32x4*)(smem + cur * 16384 + mi * 2048 + (aOff ^ 64));
        }
        // unpack B nibbles -> kb0/kb1 byte fragments
        #pragma unroll
        for (int ni = 0; ni < 4; ++ni) {
            #pragma unroll
            for (int d = 0; d < 4; ++d) {
                b0[ni][d] = bp[ni][d] & 0x0F0F0F0F;
                b1[ni][d] = (int)(((unsigned)bp[ni][d] >> 4) & 0x0F0F0F0F);
            }
        }

        WAIT_LGKM0();       // all own ds_reads of B complete before barrier
        BAR();              // => ALL waves done reading B -> safe to restage
        STAGE_B(kt + 1);    // lands under the MFMA burst below

        __builtin_amdgcn_s_setprio(1);
        #pragma unroll
        for (int mi = 0; mi < 4; ++mi)
            #pragma unroll
            for (int ni = 0; ni < 4; ++ni)
                acc[mi][ni] = __builtin_amdgcn_mfma_i32_16x16x64_i8(
                    afr[mi][0], b0[ni], acc[mi][ni], 0, 0, 0);
        #pragma unroll
        for (int mi = 0; mi < 4; ++mi)
            #pragma unroll
            for (int ni = 0; ni < 4; ++ni)
                acc[mi][ni] = __builtin_amdgcn_mfma_i32_16x16x64_i8(
                    afr[mi][1], b1[ni], acc[mi][ni], 0, 0, 0);
        __builtin_amdgcn_s_setprio(0);

        // read A rows 64..127 (reuse afr) and finish
        #pragma unroll
        for (int mi = 0; mi < 4; ++mi) {
            afr[mi][0] = *(const i32x4*)(smem + cur * 16384 + (mi + 4) * 2048 + aOff);
            afr[mi][1] = *(const i32x4*)(smem + cur * 16384 + (mi + 4) * 2048 + (aOff ^ 64));
        }
        __builtin_amdgcn_s_setprio(1);
        #pragma unroll
        for (int mi = 0; mi < 4; ++mi)
            #pragma unroll
            for (int ni = 0; ni < 4; ++ni)
                acc[mi + 4][ni] = __builtin_amdgcn_mfma_i32_16x16x64_i8(
                    afr[mi][0], b0[ni], acc[mi + 4][ni], 0, 0, 0);
        #pragma unroll
        for (int mi = 0; mi < 4; ++mi)
            #pragma unroll
            for (int ni = 0; ni < 4; ++ni)
                acc[mi + 4][ni] = __builtin_amdgcn_mfma_i32_16x16x64_i8(
                    afr[mi][1], b1[ni], acc[mi + 4][ni], 0, 0, 0);
        __builtin_amdgcn_s_setprio(0);

        WAIT_VM(0);         // A(kt+1) + B(kt+1) landed (issued >=1300cy ago)
        BAR();
    }

    // ---- epilogue: y = srow[m]*wscale[n]*acc + wadd[n]*rowsum[m] + bias[n] ----
    #pragma unroll
    for (int ni = 0; ni < 4; ++ni) {
        const int col = n0 + wv * 64 + ni * 16 + l15;
        const float sc = wscale[col];
        const float ad = wadd[col];
        const float bi = bias[col];
        #pragma unroll
        for (int mi = 0; mi < 8; ++mi) {
            const int row = m0 + mi * 16 + g * 4;
            const float4 rs4 = *(const float4*)&rowsum[row];
            const float4 sr4 = *(const float4*)&srow[row];
            #pragma unroll
            for (int j = 0; j < 4; ++j) {
                const float rs = (j == 0) ? rs4.x : (j == 1) ? rs4.y : (j == 2) ? rs4.z : rs4.w;
                const float sr = (j == 0) ? sr4.x : (j == 1) ? sr4.y : (j == 2) ? sr4.z : sr4.w;
                out[(size_t)(row + j) * OUT_DIM + col] =
                    (float)acc[mi][ni][j] * (sc * sr) + ad * rs + bi;
            }
        }
    }
}

// ---------------------------------------------------------------------------
extern "C" void kernel_launch(void* const* d_in, const int* in_sizes, int n_in,
                              void* d_out, int out_size, void* d_ws, size_t ws_size,
                              hipStream_t stream)
{
    const float* x      = (const float*)d_in[0];
    const int*   wp     = (const int*)d_in[1];
    const float* wscale = (const float*)d_in[2];
    const float* wadd   = (const float*)d_in[3];
    const float* bias   = (const float*)d_in[4];
    float*       out    = (float*)d_out;

    const int M = in_sizes[0] / IN_DIM;   // 8192

    // ws layout: [ wf4 i4 N*K/2 (8MB) | aq i8 M*K | rowsum f32 M | srow f32 M ]
    char* ws = (char*)d_ws;
    unsigned char* wf4 = (unsigned char*)ws;
    const size_t wf_bytes = (size_t)OUT_DIM * IN_DIM / 2;
    int* aq = (int*)(ws + wf_bytes);
    const size_t aq_bytes = (size_t)M * IN_DIM;
    float* rowsum = (float*)(ws + wf_bytes + aq_bytes);
    float* srow   = (float*)(ws + wf_bytes + aq_bytes + (size_t)M * 4);

    unpack_w4i<<<(OUT_DIM * 32 * 4) / 256, 256, 0, stream>>>(wp, wf4);

    had_rows_q<<<M, 256, 0, stream>>>(x, aq, rowsum, srow);

    gemm_i8<<<(M / 128) * (OUT_DIM / 256), 256, 0, stream>>>(
        (const signed char*)aq, wf4, wscale, wadd, bias, rowsum, srow, out);
}